// Round 1
// baseline (684.524 us; speedup 1.0000x reference)
//
#include <hip/hip_runtime.h>
#include <hip/hip_bf16.h>

#define DIM 128
#define BATCH 16384

// One block (256 threads = 4 waves) per batch item.
// out[b] = -( normA . (R[r] @ normT) ) = -sum_{i,j} A_i * R[i,j] * T_j
__global__ __launch_bounds__(256)
void rescal_kernel(const int* __restrict__ sample,
                   const float* __restrict__ ent,
                   const float* __restrict__ rel,
                   float* __restrict__ out) {
    const int b   = blockIdx.x;
    const int tid = threadIdx.x;
    const int wave = tid >> 6;
    const int lane = tid & 63;

    const int h = sample[b * 3 + 0];
    const int r = sample[b * 3 + 1];
    const int t = sample[b * 3 + 2];

    __shared__ float sA[DIM];   // normalized head embedding
    __shared__ float sT[DIM];   // normalized tail embedding
    __shared__ float red[4];    // per-wave partials

    // ---- load h (threads 0..127) and t (threads 128..255) embeddings ----
    float v;
    if (tid < DIM) v = ent[(size_t)h * DIM + tid];
    else           v = ent[(size_t)t * DIM + (tid - DIM)];

    // sum of squares: wave reduce (64 lanes), waves 0,1 hold A; 2,3 hold T
    float sq = v * v;
    #pragma unroll
    for (int o = 32; o > 0; o >>= 1) sq += __shfl_down(sq, o);
    if (lane == 0) red[wave] = sq;
    __syncthreads();

    const float sumA = red[0] + red[1];
    const float sumT = red[2] + red[3];
    const float inv = (tid < DIM) ? 1.0f / fmaxf(sqrtf(sumA), 1e-12f)
                                  : 1.0f / fmaxf(sqrtf(sumT), 1e-12f);
    if (tid < DIM) sA[tid] = v * inv;
    else           sT[tid - DIM] = v * inv;
    __syncthreads();

    // ---- main: sum_{i,j} A_i * R[i,j] * T_j ----
    // Flatten R[r] (128x128 fp32) into float4 chunks; thread tid, iter k
    // covers flat floats f = 1024*k + 4*tid:
    //   col j0 = (4*tid) & 127  (constant per thread)
    //   row i  = 8*k + (tid>>5)
    const float4* __restrict__ R4 = (const float4*)(rel + (size_t)r * (DIM * DIM));
    const int j0 = (tid * 4) & (DIM - 1);
    const float t0 = sT[j0 + 0];
    const float t1 = sT[j0 + 1];
    const float t2 = sT[j0 + 2];
    const float t3 = sT[j0 + 3];
    const int row0 = tid >> 5;  // 0..7

    float acc = 0.0f;
    #pragma unroll
    for (int k = 0; k < 16; ++k) {
        const float4 rv = R4[k * 256 + tid];
        const float a = sA[k * 8 + row0];
        acc += a * (rv.x * t0 + rv.y * t1 + rv.z * t2 + rv.w * t3);
    }

    // ---- block reduce acc ----
    #pragma unroll
    for (int o = 32; o > 0; o >>= 1) acc += __shfl_down(acc, o);
    __syncthreads();               // red[] reuse: prior reads are done
    if (lane == 0) red[wave] = acc;
    __syncthreads();
    if (tid == 0) out[b] = -(red[0] + red[1] + red[2] + red[3]);
}

extern "C" void kernel_launch(void* const* d_in, const int* in_sizes, int n_in,
                              void* d_out, int out_size, void* d_ws, size_t ws_size,
                              hipStream_t stream) {
    const int*   sample = (const int*)d_in[0];
    const float* ent    = (const float*)d_in[1];
    const float* rel    = (const float*)d_in[2];
    float*       out    = (float*)d_out;

    rescal_kernel<<<BATCH, 256, 0, stream>>>(sample, ent, rel, out);
}

// Round 3
// 629.823 us; speedup vs baseline: 1.0869x; 1.0869x over previous
//
#include <hip/hip_runtime.h>

#define DIM   128
#define BATCH 16384
#define NREL  500
#define CHUNK 32
#define LCAP  2048   // per-relation item-list capacity (expected max ~60)

// One block (256 threads = 4 waves) per relation.
// Phase 1: scan sample[] for items with r == blockIdx.x -> LDS list.
// Phase 2: R[r] in registers (64 floats/thread), process items in chunks
//          of 32: stage raw A/T in LDS, fold 1/norms into final scalar.
__global__ __launch_bounds__(256, 2)
void score_k(const int* __restrict__ sample, const float* __restrict__ ent,
             const float* __restrict__ rel, float* __restrict__ out) {
    const int g    = blockIdx.x;
    const int tid  = threadIdx.x;
    const int lane = tid & 63;
    const int wave = tid >> 6;
    const int row  = tid >> 1;   // 0..127: R row owned by this thread
    const int half = tid & 1;    // 0/1: which 64-col half of the row

    __shared__ int sList[LCAP];
    __shared__ int sCount;
    if (tid == 0) sCount = 0;
    __syncthreads();

    // ---- phase 1: collect this relation's items ----
    for (int b = tid; b < BATCH; b += 256) {           // 64 uniform iters
        if (sample[b * 3 + 1] == g) {
            int p = atomicAdd(&sCount, 1);
            if (p < LCAP) sList[p] = b;
        }
    }
    __syncthreads();
    const int m = min(sCount, LCAP);
    if (m == 0) return;

    // ---- R[g] into registers: 16 float4 = 64 floats per thread ----
    const float4* __restrict__ R4 = (const float4*)(rel + (size_t)g * (DIM * DIM));
    float4 Rr[16];
    #pragma unroll
    for (int q = 0; q < 16; ++q)
        Rr[q] = R4[row * 32 + half * 16 + q];

    __shared__ alignas(16) float sAT[CHUNK * 2 * DIM]; // raw A,T per item (32 KB)
    __shared__ float sNp[64][4];                       // norm partials
    __shared__ float sInv[64];                         // 1/max(||.||,1e-12)
    __shared__ float sRed[CHUNK * 4];                  // per-wave score partials

    for (int base = 0; base < m; base += CHUNK) {
        const int cact = min(CHUNK, m - base);

        // ---- stage raw A/T, 4 items per pass (one item per wave) ----
        #pragma unroll
        for (int p = 0; p < 8; ++p) {
            int c = p * 4 + wave;
            if (c < cact) {
                int gi   = sList[base + c];
                int eidx = (lane < 32) ? sample[gi * 3 + 0] : sample[gi * 3 + 2];
                int e    = (lane & 31) * 4;
                float4 v = *(const float4*)(ent + (size_t)eidx * DIM + e);
                *(float4*)&sAT[c * 256 + (lane < 32 ? 0 : DIM) + e] = v;
            }
        }
        __syncthreads();

        // ---- norms: vector v = tid>>2 (A=2c, T=2c+1), quarter q = tid&3 ----
        {
            int v = tid >> 2, q = tid & 3;
            float s = 0.f;
            if (v < cact * 2) {
                const float4* p4 = (const float4*)&sAT[v * DIM + q * 32];
                #pragma unroll
                for (int j = 0; j < 8; ++j) {
                    float4 x = p4[j];
                    s += x.x * x.x + x.y * x.y + x.z * x.z + x.w * x.w;
                }
            }
            sNp[v][q] = s;
        }
        __syncthreads();
        if (tid < 64) {
            float s = sNp[tid][0] + sNp[tid][1] + sNp[tid][2] + sNp[tid][3];
            sInv[tid] = 1.0f / fmaxf(sqrtf(s), 1e-12f);
        }

        // ---- main: per item, acc = sum_j R[row][j]*T[j] over this half ----
        for (int c = 0; c < cact; ++c) {
            const float4* T4 = (const float4*)&sAT[c * 256 + DIM + half * 64];
            float acc = 0.f;
            #pragma unroll
            for (int q = 0; q < 16; ++q) {
                float4 tv = T4[q];
                acc = fmaf(Rr[q].x, tv.x, acc);
                acc = fmaf(Rr[q].y, tv.y, acc);
                acc = fmaf(Rr[q].z, tv.z, acc);
                acc = fmaf(Rr[q].w, tv.w, acc);
            }
            float pt = sAT[c * 256 + row] * acc;   // A[row] * partial
            #pragma unroll
            for (int o = 32; o > 0; o >>= 1) pt += __shfl_down(pt, o);
            if (lane == 0) sRed[c * 4 + wave] = pt;
        }
        __syncthreads();

        // ---- epilogue: combine wave partials, fold 1/norms, write out ----
        if (tid < cact) {
            float s = sRed[tid * 4] + sRed[tid * 4 + 1]
                    + sRed[tid * 4 + 2] + sRed[tid * 4 + 3];
            out[sList[base + tid]] = -s * sInv[tid * 2] * sInv[tid * 2 + 1];
        }
        __syncthreads();   // protect sAT before next chunk
    }
}

extern "C" void kernel_launch(void* const* d_in, const int* in_sizes, int n_in,
                              void* d_out, int out_size, void* d_ws, size_t ws_size,
                              hipStream_t stream) {
    const int*   sample = (const int*)d_in[0];
    const float* ent    = (const float*)d_in[1];
    const float* rel    = (const float*)d_in[2];
    float*       out    = (float*)d_out;

    score_k<<<NREL, 256, 0, stream>>>(sample, ent, rel, out);
}